// Round 1
// baseline (2337.456 us; speedup 1.0000x reference)
//
#include <hip/hip_runtime.h>

#define B_ 2
#define P_ 256
#define TL_ 1280
#define T_ 1536
#define H_ 1024
#define HEADS_ 16
#define HD_ 64
#define NL_ 2
#define V_ 32000
#define F_ 4096
#define BT_ (B_ * T_)

typedef __attribute__((ext_vector_type(4))) float f32x4;
typedef __attribute__((ext_vector_type(8))) short short8;
typedef __attribute__((ext_vector_type(4))) short short4v;

__device__ inline short f2bf(float f) {
    union { float f; unsigned u; } v; v.f = f;
    unsigned r = v.u + 0x7FFF + ((v.u >> 16) & 1);
    return (short)(r >> 16);
}

// ---------------- embed + concat ----------------
__global__ __launch_bounds__(256) void k_embed(const float* __restrict__ prefix,
                                               const int* __restrict__ ids,
                                               const float* __restrict__ emb,
                                               float* __restrict__ x) {
    int r = blockIdx.x;                 // 0..BT-1
    int b = r / T_, t = r % T_;
    const float* src = (t < P_) ? (prefix + (size_t)(b * P_ + t) * H_)
                                : (emb + (size_t)ids[b * TL_ + (t - P_)] * H_);
    float* dst = x + (size_t)r * H_;
    int c = threadIdx.x * 4;
    *(f32x4*)&dst[c] = *(const f32x4*)&src[c];
}

// ---------------- layernorm -> bf16 ----------------
__global__ __launch_bounds__(256) void k_ln(const float* __restrict__ x,
                                            const float* __restrict__ g,
                                            const float* __restrict__ b,
                                            short* __restrict__ out) {
    int r = blockIdx.x;
    const float* xr = x + (size_t)r * H_;
    int tid = threadIdx.x;
    f32x4 v = *(const f32x4*)&xr[tid * 4];
    float s = v[0] + v[1] + v[2] + v[3];
    float sq = v[0] * v[0] + v[1] * v[1] + v[2] * v[2] + v[3] * v[3];
#pragma unroll
    for (int off = 32; off; off >>= 1) {
        s += __shfl_down(s, off, 64);
        sq += __shfl_down(sq, off, 64);
    }
    __shared__ float red[10];
    int wid = tid >> 6;
    if ((tid & 63) == 0) { red[wid] = s; red[4 + wid] = sq; }
    __syncthreads();
    if (tid == 0) {
        float S = red[0] + red[1] + red[2] + red[3];
        float SQ = red[4] + red[5] + red[6] + red[7];
        float mu = S * (1.0f / H_);
        float var = SQ * (1.0f / H_) - mu * mu;
        red[8] = mu;
        red[9] = rsqrtf(var + 1e-5f);
    }
    __syncthreads();
    float mu = red[8], rstd = red[9];
    short o[4];
#pragma unroll
    for (int j = 0; j < 4; ++j)
        o[j] = f2bf((v[j] - mu) * rstd * g[tid * 4 + j] + b[tid * 4 + j]);
    *(short4v*)&out[(size_t)r * H_ + tid * 4] = *(short4v*)o;
}

// ---------------- GEMM: C = A(bf16[M,K]) * B(f32[K,N] -> bf16) ----------------
// STORE: 0 = f32 row-major, 1 = bf16 row-major, 2 = bf16 vT scatter [B,HEADS,HD,T]
template <int STORE, bool HAS_BIAS, bool SILU, bool RES>
__global__ __launch_bounds__(256) void k_gemm(const short* __restrict__ A,
                                              const float* __restrict__ Bw,
                                              const float* __restrict__ bias,
                                              const float* __restrict__ resid,
                                              void* __restrict__ outp,
                                              int M, int N, int K, float alpha) {
    __shared__ short As[128][40];   // [m][k], 80B stride (16B aligned, bank-spread)
    __shared__ short Bs[128][40];   // [n][k]
    int tid = threadIdx.x;
    int lane = tid & 63, w = tid >> 6;
    int wr = w >> 1, wc = w & 1;
    int mbase = blockIdx.y * 128, nbase = blockIdx.x * 128;
    int lr = lane & 15, lk = (lane >> 4) * 8, lg = (lane >> 4) * 4;

    f32x4 acc[4][4] = {};

    // precomputed staging coordinates
    int ar0 = (tid + 0) >> 2, ak0 = ((tid + 0) & 3) * 8;
    int ar1 = (tid + 256) >> 2, ak1 = ((tid + 256) & 3) * 8;

    for (int kb = 0; kb < K; kb += 32) {
        __syncthreads();
        // stage A (bf16 direct)
        *(short8*)&As[ar0][ak0] = *(const short8*)&A[(size_t)(mbase + ar0) * K + kb + ak0];
        *(short8*)&As[ar1][ak1] = *(const short8*)&A[(size_t)(mbase + ar1) * K + kb + ak1];
        // stage B (f32 -> bf16, transposed to [n][k])
#pragma unroll
        for (int c = 0; c < 4; ++c) {
            int chunk = tid + 256 * c;
            int k = chunk >> 5, n4 = (chunk & 31) * 4;
            f32x4 bv = *(const f32x4*)&Bw[(size_t)(kb + k) * N + nbase + n4];
            Bs[n4 + 0][k] = f2bf(bv[0]);
            Bs[n4 + 1][k] = f2bf(bv[1]);
            Bs[n4 + 2][k] = f2bf(bv[2]);
            Bs[n4 + 3][k] = f2bf(bv[3]);
        }
        __syncthreads();
        short8 af[4], bfr[4];
#pragma unroll
        for (int mi = 0; mi < 4; ++mi) af[mi] = *(short8*)&As[wr * 64 + mi * 16 + lr][lk];
#pragma unroll
        for (int ni = 0; ni < 4; ++ni) bfr[ni] = *(short8*)&Bs[wc * 64 + ni * 16 + lr][lk];
#pragma unroll
        for (int mi = 0; mi < 4; ++mi)
#pragma unroll
            for (int ni = 0; ni < 4; ++ni)
                acc[mi][ni] = __builtin_amdgcn_mfma_f32_16x16x32_bf16(af[mi], bfr[ni], acc[mi][ni], 0, 0, 0);
    }

    // epilogue
#pragma unroll
    for (int ni = 0; ni < 4; ++ni) {
        int col = nbase + wc * 64 + ni * 16 + lr;
        float bv = HAS_BIAS ? bias[col] : 0.f;
#pragma unroll
        for (int mi = 0; mi < 4; ++mi) {
#pragma unroll
            for (int j = 0; j < 4; ++j) {
                int row = mbase + wr * 64 + mi * 16 + lg + j;
                float vv = acc[mi][ni][j] * alpha + bv;
                if (SILU) vv = vv / (1.f + __expf(-vv));
                if (RES) vv += resid[(size_t)row * N + col];
                if (STORE == 0) {
                    ((float*)outp)[(size_t)row * N + col] = vv;
                } else if (STORE == 1) {
                    ((short*)outp)[(size_t)row * N + col] = f2bf(vv);
                } else {
                    int bb = row / T_, t = row % T_;
                    int head = col >> 6, hd = col & 63;
                    ((short*)outp)[((size_t)(bb * HEADS_ + head) * HD_ + hd) * T_ + t] = f2bf(vv);
                }
            }
        }
    }
}

// ---------------- flash attention ----------------
// grid (T/64, HEADS, B); 4 waves, each owns 16 q-rows. q pre-scaled by 1/8.
__global__ __launch_bounds__(256) void k_attn(const short* __restrict__ q,
                                              const short* __restrict__ k,
                                              const short* __restrict__ vT,
                                              short* __restrict__ out) {
    int qt = blockIdx.x, head = blockIdx.y, b = blockIdx.z;
    int qbase = qt * 64;
    __shared__ short Qs[64][72];
    __shared__ short Ps[4][16][72];
    int tid = threadIdx.x, lane = tid & 63, w = tid >> 6;
    int lr = lane & 15, lg4 = (lane >> 4) * 4, lk8 = (lane >> 4) * 8;

    // stage Q tile [64 rows][64 hd]
#pragma unroll
    for (int c = 0; c < 2; ++c) {
        int chunk = tid + 256 * c;
        int row = chunk >> 3, h8 = (chunk & 7) * 8;
        *(short8*)&Qs[row][h8] =
            *(const short8*)&q[(size_t)(b * T_ + qbase + row) * H_ + head * HD_ + h8];
    }
    __syncthreads();

    short8 qf[2];
    qf[0] = *(short8*)&Qs[w * 16 + lr][lk8];
    qf[1] = *(short8*)&Qs[w * 16 + lr][32 + lk8];

    f32x4 o[4] = {};
    float m[4] = {-1e30f, -1e30f, -1e30f, -1e30f};
    float lsum[4] = {0.f, 0.f, 0.f, 0.f};

    for (int kt = 0; kt <= qt; ++kt) {
        int kb = kt * 64;
        f32x4 s[4] = {};
#pragma unroll
        for (int ks = 0; ks < 2; ++ks) {
#pragma unroll
            for (int f = 0; f < 4; ++f) {
                short8 kf = *(const short8*)&k[(size_t)(b * T_ + kb + f * 16 + lr) * H_ +
                                               head * HD_ + ks * 32 + lk8];
                s[f] = __builtin_amdgcn_mfma_f32_16x16x32_bf16(qf[ks], kf, s[f], 0, 0, 0);
            }
        }
        // causal mask (only diagonal tile)
        if (kt == qt) {
#pragma unroll
            for (int f = 0; f < 4; ++f) {
                int key = kb + f * 16 + lr;
#pragma unroll
                for (int j = 0; j < 4; ++j) {
                    int qrow = qbase + w * 16 + lg4 + j;
                    if (key > qrow) s[f][j] = -1e30f;
                }
            }
        }
        // online softmax per row (rows owned by 16-lane groups)
#pragma unroll
        for (int j = 0; j < 4; ++j) {
            float mx = fmaxf(fmaxf(s[0][j], s[1][j]), fmaxf(s[2][j], s[3][j]));
#pragma unroll
            for (int off = 1; off < 16; off <<= 1) mx = fmaxf(mx, __shfl_xor(mx, off, 64));
            float mnew = fmaxf(m[j], mx);
            float sc = __expf(m[j] - mnew);
            m[j] = mnew;
            float rs = 0.f;
#pragma unroll
            for (int f = 0; f < 4; ++f) {
                float p = __expf(s[f][j] - mnew);
                s[f][j] = p;
                rs += p;
            }
#pragma unroll
            for (int off = 1; off < 16; off <<= 1) rs += __shfl_xor(rs, off, 64);
            lsum[j] = lsum[j] * sc + rs;
#pragma unroll
            for (int f = 0; f < 4; ++f) o[f][j] *= sc;
#pragma unroll
            for (int f = 0; f < 4; ++f) Ps[w][lg4 + j][f * 16 + lr] = f2bf(s[f][j]);
        }
        // PV
#pragma unroll
        for (int ks2 = 0; ks2 < 2; ++ks2) {
            short8 pf = *(short8*)&Ps[w][lr][ks2 * 32 + lk8];
#pragma unroll
            for (int f = 0; f < 4; ++f) {
                short8 vf = *(const short8*)&vT[((size_t)(b * HEADS_ + head) * HD_ + f * 16 + lr) * T_ +
                                                kb + ks2 * 32 + lk8];
                o[f] = __builtin_amdgcn_mfma_f32_16x16x32_bf16(pf, vf, o[f], 0, 0, 0);
            }
        }
    }
    // normalize + store
#pragma unroll
    for (int f = 0; f < 4; ++f)
#pragma unroll
        for (int j = 0; j < 4; ++j) {
            float val = o[f][j] / lsum[j];
            out[(size_t)(b * T_ + qbase + w * 16 + lg4 + j) * H_ + head * HD_ + f * 16 + lr] =
                f2bf(val);
        }
}

// ---------------- launch ----------------
extern "C" void kernel_launch(void* const* d_in, const int* in_sizes, int n_in,
                              void* d_out, int out_size, void* d_ws, size_t ws_size,
                              hipStream_t stream) {
    const float* prefix = (const float*)d_in[0];
    const int* ids = (const int*)d_in[1];
    const float* emb = (const float*)d_in[2];
    const float* Wq = (const float*)d_in[3];
    const float* Wk = (const float*)d_in[4];
    const float* Wv = (const float*)d_in[5];
    const float* Wo = (const float*)d_in[6];
    const float* g1 = (const float*)d_in[7];
    const float* b1 = (const float*)d_in[8];
    const float* g2 = (const float*)d_in[9];
    const float* b2 = (const float*)d_in[10];
    const float* W1 = (const float*)d_in[11];
    const float* bm1 = (const float*)d_in[12];
    const float* W2 = (const float*)d_in[13];
    const float* bm2 = (const float*)d_in[14];
    const float* gf = (const float*)d_in[15];
    const float* bf = (const float*)d_in[16];
    const float* Whead = (const float*)d_in[17];
    float* out = (float*)d_out;

    char* wsp = (char*)d_ws;
    float* x = (float*)wsp;  wsp += (size_t)BT_ * H_ * 4;
    short* h = (short*)wsp;  wsp += (size_t)BT_ * H_ * 2;
    short* qb = (short*)wsp; wsp += (size_t)BT_ * H_ * 2;
    short* kb = (short*)wsp; wsp += (size_t)BT_ * H_ * 2;
    short* vT = (short*)wsp; wsp += (size_t)BT_ * H_ * 2;
    short* ao = (short*)wsp; wsp += (size_t)BT_ * H_ * 2;
    short* mid = (short*)wsp; wsp += (size_t)BT_ * F_ * 2;

    dim3 blk(256);
    k_embed<<<BT_, blk, 0, stream>>>(prefix, ids, emb, x);
    for (int l = 0; l < NL_; ++l) {
        k_ln<<<BT_, blk, 0, stream>>>(x, g1 + l * H_, b1 + l * H_, h);
        k_gemm<1, false, false, false><<<dim3(8, 24), blk, 0, stream>>>(
            h, Wq + (size_t)l * H_ * H_, nullptr, nullptr, qb, BT_, H_, H_, 0.125f);
        k_gemm<1, false, false, false><<<dim3(8, 24), blk, 0, stream>>>(
            h, Wk + (size_t)l * H_ * H_, nullptr, nullptr, kb, BT_, H_, H_, 1.f);
        k_gemm<2, false, false, false><<<dim3(8, 24), blk, 0, stream>>>(
            h, Wv + (size_t)l * H_ * H_, nullptr, nullptr, vT, BT_, H_, H_, 1.f);
        k_attn<<<dim3(T_ / 64, HEADS_, B_), blk, 0, stream>>>(qb, kb, vT, ao);
        k_gemm<0, false, false, true><<<dim3(8, 24), blk, 0, stream>>>(
            ao, Wo + (size_t)l * H_ * H_, nullptr, x, x, BT_, H_, H_, 1.f);
        k_ln<<<BT_, blk, 0, stream>>>(x, g2 + l * H_, b2 + l * H_, h);
        k_gemm<1, true, true, false><<<dim3(32, 24), blk, 0, stream>>>(
            h, W1 + (size_t)l * H_ * F_, bm1 + (size_t)l * F_, nullptr, mid, BT_, F_, H_, 1.f);
        k_gemm<0, true, false, true><<<dim3(8, 24), blk, 0, stream>>>(
            mid, W2 + (size_t)l * F_ * H_, bm2 + (size_t)l * H_, x, x, BT_, H_, F_, 1.f);
    }
    k_ln<<<BT_, blk, 0, stream>>>(x, gf, bf, h);
    k_gemm<0, false, false, false><<<dim3(V_ / 128, BT_ / 128), blk, 0, stream>>>(
        h, Whead, nullptr, nullptr, out, BT_, V_, H_, 1.f);
}

// Round 2
// 1273.108 us; speedup vs baseline: 1.8360x; 1.8360x over previous
//
#include <hip/hip_runtime.h>
#include <stdint.h>

#define B_ 2
#define P_ 256
#define TL_ 1280
#define T_ 1536
#define H_ 1024
#define HEADS_ 16
#define HD_ 64
#define NL_ 2
#define V_ 32000
#define F_ 4096
#define BT_ (B_ * T_)

typedef __attribute__((ext_vector_type(4))) float f32x4;
typedef __attribute__((ext_vector_type(8))) short short8;
typedef __attribute__((ext_vector_type(4))) short short4v;

typedef __attribute__((address_space(3))) uint32_t lds_u32_t;
typedef const __attribute__((address_space(1))) uint32_t glb_u32_t;

__device__ inline void gload_lds16(const void* g, void* l) {
    __builtin_amdgcn_global_load_lds((glb_u32_t*)g, (lds_u32_t*)l, 16, 0, 0);
}

__device__ inline short f2bf(float f) {
    union { float f; unsigned u; } v; v.f = f;
    unsigned r = v.u + 0x7FFF + ((v.u >> 16) & 1);
    return (short)(r >> 16);
}

// ---------------- embed + concat ----------------
__global__ __launch_bounds__(256) void k_embed(const float* __restrict__ prefix,
                                               const int* __restrict__ ids,
                                               const float* __restrict__ emb,
                                               float* __restrict__ x) {
    int r = blockIdx.x;
    int b = r / T_, t = r % T_;
    const float* src = (t < P_) ? (prefix + (size_t)(b * P_ + t) * H_)
                                : (emb + (size_t)ids[b * TL_ + (t - P_)] * H_);
    float* dst = x + (size_t)r * H_;
    int c = threadIdx.x * 4;
    *(f32x4*)&dst[c] = *(const f32x4*)&src[c];
}

// ---------------- weight transpose-convert: f32 [K,N] -> bf16 [N,K] ----------
__global__ __launch_bounds__(256) void k_cvt_t(const float* __restrict__ W,
                                               short* __restrict__ Wt,
                                               int K, int N) {
    __shared__ float tile[32][36];
    int nb = blockIdx.x * 32, kb = blockIdx.y * 32;
    int tid = threadIdx.x;
    int r = tid >> 3, c4 = (tid & 7) * 4;
    f32x4 v = *(const f32x4*)&W[(size_t)(kb + r) * N + nb + c4];
    *(f32x4*)&tile[r][c4] = v;
    __syncthreads();
    int wn = tid >> 3, wk4 = (tid & 7) * 4;
    short o[4];
#pragma unroll
    for (int j = 0; j < 4; ++j) o[j] = f2bf(tile[wk4 + j][wn]);
    *(short4v*)&Wt[(size_t)(nb + wn) * K + kb + wk4] = *(short4v*)o;
}

// ---------------- layernorm -> bf16 ----------------
__global__ __launch_bounds__(256) void k_ln(const float* __restrict__ x,
                                            const float* __restrict__ g,
                                            const float* __restrict__ b,
                                            short* __restrict__ out) {
    int r = blockIdx.x;
    const float* xr = x + (size_t)r * H_;
    int tid = threadIdx.x;
    f32x4 v = *(const f32x4*)&xr[tid * 4];
    float s = v[0] + v[1] + v[2] + v[3];
    float sq = v[0] * v[0] + v[1] * v[1] + v[2] * v[2] + v[3] * v[3];
#pragma unroll
    for (int off = 32; off; off >>= 1) {
        s += __shfl_down(s, off, 64);
        sq += __shfl_down(sq, off, 64);
    }
    __shared__ float red[10];
    int wid = tid >> 6;
    if ((tid & 63) == 0) { red[wid] = s; red[4 + wid] = sq; }
    __syncthreads();
    if (tid == 0) {
        float S = red[0] + red[1] + red[2] + red[3];
        float SQ = red[4] + red[5] + red[6] + red[7];
        float mu = S * (1.0f / H_);
        float var = SQ * (1.0f / H_) - mu * mu;
        red[8] = mu;
        red[9] = rsqrtf(var + 1e-5f);
    }
    __syncthreads();
    float mu = red[8], rstd = red[9];
    short o[4];
#pragma unroll
    for (int j = 0; j < 4; ++j)
        o[j] = f2bf((v[j] - mu) * rstd * g[tid * 4 + j] + b[tid * 4 + j]);
    *(short4v*)&out[(size_t)r * H_ + tid * 4] = *(short4v*)o;
}

// ---------------- GEMM: C = A(bf16[M,K]) * Bt(bf16[N,K])^T -------------------
// m97 structure: 128x128 tile, BK=32, linear LDS, global_load_lds width 16.
// STORE: 0 = f32 row-major, 1 = bf16 row-major, 2 = bf16 vT scatter [B,HEADS,HD,T]
template <int STORE, bool HAS_BIAS, bool SILU, bool RES>
__global__ __launch_bounds__(256) void k_gemm(const short* __restrict__ A,
                                              const short* __restrict__ Bt,
                                              const float* __restrict__ bias,
                                              const float* __restrict__ resid,
                                              void* __restrict__ outp,
                                              int M, int N, int K, float alpha) {
    __shared__ short As[128 * 32];
    __shared__ short Bs[128 * 32];
    int tid = threadIdx.x;
    int lane = tid & 63, w = tid >> 6;
    int wr = w >> 1, wc = w & 1;
    // bijective XCD swizzle (nwg % 8 == 0 for all our grids), M-major tile order
    int nwg = gridDim.x;
    int mblocks = M >> 7;
    int cpx = nwg >> 3;
    int logical = (blockIdx.x & 7) * cpx + (blockIdx.x >> 3);
    int rp = logical % mblocks, cp = logical / mblocks;
    int mbase = rp * 128, nbase = cp * 128;
    int lr = lane & 15, hi = lane >> 4;
    int lk = hi * 8, lg = hi * 4;

    f32x4 acc[4][4] = {};

    int c0 = tid, c1 = tid + 256;
    int ar0 = c0 >> 2, ak0 = (c0 & 3) * 8;
    int ar1 = c1 >> 2, ak1 = (c1 & 3) * 8;
    const short* Ab = A + (size_t)mbase * K;
    const short* Bb = Bt + (size_t)nbase * K;

    for (int kb = 0; kb < K; kb += 32) {
        __syncthreads();
        gload_lds16(Ab + (size_t)ar0 * K + kb + ak0, &As[c0 * 8]);
        gload_lds16(Ab + (size_t)ar1 * K + kb + ak1, &As[c1 * 8]);
        gload_lds16(Bb + (size_t)ar0 * K + kb + ak0, &Bs[c0 * 8]);
        gload_lds16(Bb + (size_t)ar1 * K + kb + ak1, &Bs[c1 * 8]);
        __syncthreads();
        short8 af[4], bfr[4];
#pragma unroll
        for (int mi = 0; mi < 4; ++mi) af[mi] = *(short8*)&As[(wr * 64 + mi * 16 + lr) * 32 + lk];
#pragma unroll
        for (int ni = 0; ni < 4; ++ni) bfr[ni] = *(short8*)&Bs[(wc * 64 + ni * 16 + lr) * 32 + lk];
#pragma unroll
        for (int mi = 0; mi < 4; ++mi)
#pragma unroll
            for (int ni = 0; ni < 4; ++ni)
                acc[mi][ni] = __builtin_amdgcn_mfma_f32_16x16x32_bf16(af[mi], bfr[ni], acc[mi][ni], 0, 0, 0);
    }

    // epilogue (C mapping verified in round 0: row = m-frag, col = n-frag)
#pragma unroll
    for (int ni = 0; ni < 4; ++ni) {
        int col = nbase + wc * 64 + ni * 16 + lr;
        float bv = HAS_BIAS ? bias[col] : 0.f;
#pragma unroll
        for (int mi = 0; mi < 4; ++mi) {
#pragma unroll
            for (int j = 0; j < 4; ++j) {
                int row = mbase + wr * 64 + mi * 16 + lg + j;
                float vv = acc[mi][ni][j] * alpha + bv;
                if (SILU) vv = vv / (1.f + __expf(-vv));
                if (RES) vv += resid[(size_t)row * N + col];
                if (STORE == 0) {
                    ((float*)outp)[(size_t)row * N + col] = vv;
                } else if (STORE == 1) {
                    ((short*)outp)[(size_t)row * N + col] = f2bf(vv);
                } else {
                    int bb = row / T_, t = row % T_;
                    int head = col >> 6, hd = col & 63;
                    ((short*)outp)[((size_t)(bb * HEADS_ + head) * HD_ + hd) * T_ + t] = f2bf(vv);
                }
            }
        }
    }
}

// ---------------- flash attention ----------------
__global__ __launch_bounds__(256) void k_attn(const short* __restrict__ q,
                                              const short* __restrict__ k,
                                              const short* __restrict__ vT,
                                              short* __restrict__ out) {
    int qt = blockIdx.x, head = blockIdx.y, b = blockIdx.z;
    int qbase = qt * 64;
    __shared__ short Qs[64][72];
    __shared__ short Ps[4][16][72];
    int tid = threadIdx.x, lane = tid & 63, w = tid >> 6;
    int lr = lane & 15, lg4 = (lane >> 4) * 4, lk8 = (lane >> 4) * 8;

#pragma unroll
    for (int c = 0; c < 2; ++c) {
        int chunk = tid + 256 * c;
        int row = chunk >> 3, h8 = (chunk & 7) * 8;
        *(short8*)&Qs[row][h8] =
            *(const short8*)&q[(size_t)(b * T_ + qbase + row) * H_ + head * HD_ + h8];
    }
    __syncthreads();

    short8 qf[2];
    qf[0] = *(short8*)&Qs[w * 16 + lr][lk8];
    qf[1] = *(short8*)&Qs[w * 16 + lr][32 + lk8];

    f32x4 o[4] = {};
    float m[4] = {-1e30f, -1e30f, -1e30f, -1e30f};
    float lsum[4] = {0.f, 0.f, 0.f, 0.f};

    for (int kt = 0; kt <= qt; ++kt) {
        int kb = kt * 64;
        f32x4 s[4] = {};
#pragma unroll
        for (int ks = 0; ks < 2; ++ks) {
#pragma unroll
            for (int f = 0; f < 4; ++f) {
                short8 kf = *(const short8*)&k[(size_t)(b * T_ + kb + f * 16 + lr) * H_ +
                                               head * HD_ + ks * 32 + lk8];
                s[f] = __builtin_amdgcn_mfma_f32_16x16x32_bf16(qf[ks], kf, s[f], 0, 0, 0);
            }
        }
        if (kt == qt) {
#pragma unroll
            for (int f = 0; f < 4; ++f) {
                int key = kb + f * 16 + lr;
#pragma unroll
                for (int j = 0; j < 4; ++j) {
                    int qrow = qbase + w * 16 + lg4 + j;
                    if (key > qrow) s[f][j] = -1e30f;
                }
            }
        }
#pragma unroll
        for (int j = 0; j < 4; ++j) {
            float mx = fmaxf(fmaxf(s[0][j], s[1][j]), fmaxf(s[2][j], s[3][j]));
#pragma unroll
            for (int off = 1; off < 16; off <<= 1) mx = fmaxf(mx, __shfl_xor(mx, off, 64));
            float mnew = fmaxf(m[j], mx);
            float sc = __expf(m[j] - mnew);
            m[j] = mnew;
            float rs = 0.f;
#pragma unroll
            for (int f = 0; f < 4; ++f) {
                float p = __expf(s[f][j] - mnew);
                s[f][j] = p;
                rs += p;
            }
#pragma unroll
            for (int off = 1; off < 16; off <<= 1) rs += __shfl_xor(rs, off, 64);
            lsum[j] = lsum[j] * sc + rs;
#pragma unroll
            for (int f = 0; f < 4; ++f) o[f][j] *= sc;
#pragma unroll
            for (int f = 0; f < 4; ++f) Ps[w][lg4 + j][f * 16 + lr] = f2bf(s[f][j]);
        }
#pragma unroll
        for (int ks2 = 0; ks2 < 2; ++ks2) {
            short8 pf = *(short8*)&Ps[w][lr][ks2 * 32 + lk8];
#pragma unroll
            for (int f = 0; f < 4; ++f) {
                short8 vf = *(const short8*)&vT[((size_t)(b * HEADS_ + head) * HD_ + f * 16 + lr) * T_ +
                                                kb + ks2 * 32 + lk8];
                o[f] = __builtin_amdgcn_mfma_f32_16x16x32_bf16(pf, vf, o[f], 0, 0, 0);
            }
        }
    }
#pragma unroll
    for (int f = 0; f < 4; ++f)
#pragma unroll
        for (int j = 0; j < 4; ++j) {
            float val = o[f][j] / lsum[j];
            out[(size_t)(b * T_ + qbase + w * 16 + lg4 + j) * H_ + head * HD_ + f * 16 + lr] =
                f2bf(val);
        }
}

// ---------------- launch ----------------
extern "C" void kernel_launch(void* const* d_in, const int* in_sizes, int n_in,
                              void* d_out, int out_size, void* d_ws, size_t ws_size,
                              hipStream_t stream) {
    const float* prefix = (const float*)d_in[0];
    const int* ids = (const int*)d_in[1];
    const float* emb = (const float*)d_in[2];
    const float* Wq = (const float*)d_in[3];
    const float* Wk = (const float*)d_in[4];
    const float* Wv = (const float*)d_in[5];
    const float* Wo = (const float*)d_in[6];
    const float* g1 = (const float*)d_in[7];
    const float* b1 = (const float*)d_in[8];
    const float* g2 = (const float*)d_in[9];
    const float* b2 = (const float*)d_in[10];
    const float* W1 = (const float*)d_in[11];
    const float* bm1 = (const float*)d_in[12];
    const float* W2 = (const float*)d_in[13];
    const float* bm2 = (const float*)d_in[14];
    const float* gf = (const float*)d_in[15];
    const float* bf = (const float*)d_in[16];
    const float* Whead = (const float*)d_in[17];
    float* out = (float*)d_out;

    char* wsp = (char*)d_ws;
    float* x = (float*)wsp;   wsp += (size_t)BT_ * H_ * 4;
    short* h = (short*)wsp;   wsp += (size_t)BT_ * H_ * 2;
    short* qb = (short*)wsp;  wsp += (size_t)BT_ * H_ * 2;
    short* kb = (short*)wsp;  wsp += (size_t)BT_ * H_ * 2;
    short* vT = (short*)wsp;  wsp += (size_t)BT_ * H_ * 2;
    short* ao = (short*)wsp;  wsp += (size_t)BT_ * H_ * 2;
    short* mid = (short*)wsp; wsp += (size_t)BT_ * F_ * 2;
    // bf16-transposed weights [N][K]
    short* WqT = (short*)wsp; wsp += (size_t)NL_ * H_ * H_ * 2;
    short* WkT = (short*)wsp; wsp += (size_t)NL_ * H_ * H_ * 2;
    short* WvT = (short*)wsp; wsp += (size_t)NL_ * H_ * H_ * 2;
    short* WoT = (short*)wsp; wsp += (size_t)NL_ * H_ * H_ * 2;
    short* W1T = (short*)wsp; wsp += (size_t)NL_ * H_ * F_ * 2;
    short* W2T = (short*)wsp; wsp += (size_t)NL_ * F_ * H_ * 2;
    short* WhT = (short*)wsp; wsp += (size_t)H_ * V_ * 2;

    dim3 blk(256);
    // weight conversion (once per call; read-once f32 -> bf16 [N][K])
    for (int l = 0; l < NL_; ++l) {
        size_t o1 = (size_t)l * H_ * H_;
        k_cvt_t<<<dim3(H_ / 32, H_ / 32), blk, 0, stream>>>(Wq + o1, WqT + o1, H_, H_);
        k_cvt_t<<<dim3(H_ / 32, H_ / 32), blk, 0, stream>>>(Wk + o1, WkT + o1, H_, H_);
        k_cvt_t<<<dim3(H_ / 32, H_ / 32), blk, 0, stream>>>(Wv + o1, WvT + o1, H_, H_);
        k_cvt_t<<<dim3(H_ / 32, H_ / 32), blk, 0, stream>>>(Wo + o1, WoT + o1, H_, H_);
        size_t o2 = (size_t)l * H_ * F_;
        k_cvt_t<<<dim3(F_ / 32, H_ / 32), blk, 0, stream>>>(W1 + o2, W1T + o2, H_, F_);
        k_cvt_t<<<dim3(H_ / 32, F_ / 32), blk, 0, stream>>>(W2 + o2, W2T + o2, F_, H_);
    }
    k_cvt_t<<<dim3(V_ / 32, H_ / 32), blk, 0, stream>>>(Whead, WhT, H_, V_);

    k_embed<<<BT_, blk, 0, stream>>>(prefix, ids, emb, x);
    for (int l = 0; l < NL_; ++l) {
        size_t o1 = (size_t)l * H_ * H_;
        size_t o2 = (size_t)l * H_ * F_;
        k_ln<<<BT_, blk, 0, stream>>>(x, g1 + l * H_, b1 + l * H_, h);
        k_gemm<1, false, false, false><<<dim3(192), blk, 0, stream>>>(
            h, WqT + o1, nullptr, nullptr, qb, BT_, H_, H_, 0.125f);
        k_gemm<1, false, false, false><<<dim3(192), blk, 0, stream>>>(
            h, WkT + o1, nullptr, nullptr, kb, BT_, H_, H_, 1.f);
        k_gemm<2, false, false, false><<<dim3(192), blk, 0, stream>>>(
            h, WvT + o1, nullptr, nullptr, vT, BT_, H_, H_, 1.f);
        k_attn<<<dim3(T_ / 64, HEADS_, B_), blk, 0, stream>>>(qb, kb, vT, ao);
        k_gemm<0, false, false, true><<<dim3(192), blk, 0, stream>>>(
            ao, WoT + o1, nullptr, x, x, BT_, H_, H_, 1.f);
        k_ln<<<BT_, blk, 0, stream>>>(x, g2 + l * H_, b2 + l * H_, h);
        k_gemm<1, true, true, false><<<dim3(768), blk, 0, stream>>>(
            h, W1T + o2, bm1 + (size_t)l * F_, nullptr, mid, BT_, F_, H_, 1.f);
        k_gemm<0, true, false, true><<<dim3(192), blk, 0, stream>>>(
            mid, W2T + o2, bm2 + (size_t)l * H_, x, x, BT_, H_, F_, 1.f);
    }
    k_ln<<<BT_, blk, 0, stream>>>(x, gf, bf, h);
    k_gemm<0, false, false, false><<<dim3(6000), blk, 0, stream>>>(
        h, WhT, nullptr, nullptr, out, BT_, V_, H_, 1.f);
}

// Round 3
// 1122.436 us; speedup vs baseline: 2.0825x; 1.1342x over previous
//
#include <hip/hip_runtime.h>
#include <stdint.h>

#define B_ 2
#define P_ 256
#define TL_ 1280
#define T_ 1536
#define H_ 1024
#define HEADS_ 16
#define HD_ 64
#define NL_ 2
#define V_ 32000
#define F_ 4096
#define BT_ (B_ * T_)

typedef __attribute__((ext_vector_type(4))) float f32x4;
typedef __attribute__((ext_vector_type(8))) short short8;
typedef __attribute__((ext_vector_type(4))) short short4v;

typedef __attribute__((address_space(3))) uint32_t lds_u32_t;
typedef const __attribute__((address_space(1))) uint32_t glb_u32_t;

__device__ inline void gload_lds16(const void* g, void* l) {
    __builtin_amdgcn_global_load_lds((glb_u32_t*)g, (lds_u32_t*)l, 16, 0, 0);
}

__device__ inline short f2bf(float f) {
    union { float f; unsigned u; } v; v.f = f;
    unsigned r = v.u + 0x7FFF + ((v.u >> 16) & 1);
    return (short)(r >> 16);
}

#define BAR() asm volatile("s_barrier" ::: "memory")

// ---------------- embed + concat ----------------
__global__ __launch_bounds__(256) void k_embed(const float* __restrict__ prefix,
                                               const int* __restrict__ ids,
                                               const float* __restrict__ emb,
                                               float* __restrict__ x) {
    int r = blockIdx.x;
    int b = r / T_, t = r % T_;
    const float* src = (t < P_) ? (prefix + (size_t)(b * P_ + t) * H_)
                                : (emb + (size_t)ids[b * TL_ + (t - P_)] * H_);
    float* dst = x + (size_t)r * H_;
    int c = threadIdx.x * 4;
    *(f32x4*)&dst[c] = *(const f32x4*)&src[c];
}

// ---------------- weight transpose-convert: f32 [K,N] -> bf16 [N,K] ----------
__global__ __launch_bounds__(256) void k_cvt_t(const float* __restrict__ W,
                                               short* __restrict__ Wt,
                                               int K, int N, float scale) {
    __shared__ float tile[32][36];
    int nb = blockIdx.x * 32, kb = blockIdx.y * 32;
    int tid = threadIdx.x;
    int r = tid >> 3, c4 = (tid & 7) * 4;
    f32x4 v = *(const f32x4*)&W[(size_t)(kb + r) * N + nb + c4];
    *(f32x4*)&tile[r][c4] = v;
    __syncthreads();
    int wn = tid >> 3, wk4 = (tid & 7) * 4;
    short o[4];
#pragma unroll
    for (int j = 0; j < 4; ++j) o[j] = f2bf(tile[wk4 + j][wn] * scale);
    *(short4v*)&Wt[(size_t)(nb + wn) * K + kb + wk4] = *(short4v*)o;
}

// ---------------- layernorm -> bf16 ----------------
__global__ __launch_bounds__(256) void k_ln(const float* __restrict__ x,
                                            const float* __restrict__ g,
                                            const float* __restrict__ b,
                                            short* __restrict__ out) {
    int r = blockIdx.x;
    const float* xr = x + (size_t)r * H_;
    int tid = threadIdx.x;
    f32x4 v = *(const f32x4*)&xr[tid * 4];
    float s = v[0] + v[1] + v[2] + v[3];
    float sq = v[0] * v[0] + v[1] * v[1] + v[2] * v[2] + v[3] * v[3];
#pragma unroll
    for (int off = 32; off; off >>= 1) {
        s += __shfl_down(s, off, 64);
        sq += __shfl_down(sq, off, 64);
    }
    __shared__ float red[10];
    int wid = tid >> 6;
    if ((tid & 63) == 0) { red[wid] = s; red[4 + wid] = sq; }
    __syncthreads();
    if (tid == 0) {
        float S = red[0] + red[1] + red[2] + red[3];
        float SQ = red[4] + red[5] + red[6] + red[7];
        float mu = S * (1.0f / H_);
        float var = SQ * (1.0f / H_) - mu * mu;
        red[8] = mu;
        red[9] = rsqrtf(var + 1e-5f);
    }
    __syncthreads();
    float mu = red[8], rstd = red[9];
    short o[4];
#pragma unroll
    for (int j = 0; j < 4; ++j)
        o[j] = f2bf((v[j] - mu) * rstd * g[tid * 4 + j] + b[tid * 4 + j]);
    *(short4v*)&out[(size_t)r * H_ + tid * 4] = *(short4v*)o;
}

// ---------------- m97-structure GEMM (layer GEMMs) ---------------------------
// C = A(bf16[M,K]) * Bt(bf16[N,K])^T.  128x128 tile, BK=32, linear LDS,
// global_load_lds width 16.
// STORE: 0 = f32 row-major (+resid), 1 = bf16 row-major,
//        3 = fused QKV split: cols 0-1023 -> q (bf16), 1024-2047 -> k,
//            2048-3071 -> vT scatter [B,HEADS,HD,T]
template <int STORE, bool HAS_BIAS, bool SILU, bool RES>
__global__ __launch_bounds__(256) void k_gemm(const short* __restrict__ A,
                                              const short* __restrict__ Bt,
                                              const float* __restrict__ bias,
                                              const float* __restrict__ resid,
                                              void* __restrict__ outp,
                                              void* __restrict__ outp2,
                                              void* __restrict__ outp3,
                                              int M, int N, int K, float alpha) {
    __shared__ short As[128 * 32];
    __shared__ short Bs[128 * 32];
    int tid = threadIdx.x;
    int lane = tid & 63, w = tid >> 6;
    int wr = w >> 1, wc = w & 1;
    int nwg = gridDim.x;                 // requires nwg % 8 == 0
    int mblocks = M >> 7;
    int cpx = nwg >> 3;
    int logical = (blockIdx.x & 7) * cpx + (blockIdx.x >> 3);
    int rp = logical % mblocks, cp = logical / mblocks;
    int mbase = rp * 128, nbase = cp * 128;
    int lr = lane & 15, hi = lane >> 4;
    int lk = hi * 8, lg = hi * 4;

    f32x4 acc[4][4] = {};

    int c0 = tid, c1 = tid + 256;
    int ar0 = c0 >> 2, ak0 = (c0 & 3) * 8;
    int ar1 = c1 >> 2, ak1 = (c1 & 3) * 8;
    const short* Ab = A + (size_t)mbase * K;
    const short* Bb = Bt + (size_t)nbase * K;

    for (int kb = 0; kb < K; kb += 32) {
        __syncthreads();
        gload_lds16(Ab + (size_t)ar0 * K + kb + ak0, &As[c0 * 8]);
        gload_lds16(Ab + (size_t)ar1 * K + kb + ak1, &As[c1 * 8]);
        gload_lds16(Bb + (size_t)ar0 * K + kb + ak0, &Bs[c0 * 8]);
        gload_lds16(Bb + (size_t)ar1 * K + kb + ak1, &Bs[c1 * 8]);
        __syncthreads();
        short8 af[4], bfr[4];
#pragma unroll
        for (int mi = 0; mi < 4; ++mi) af[mi] = *(short8*)&As[(wr * 64 + mi * 16 + lr) * 32 + lk];
#pragma unroll
        for (int ni = 0; ni < 4; ++ni) bfr[ni] = *(short8*)&Bs[(wc * 64 + ni * 16 + lr) * 32 + lk];
#pragma unroll
        for (int mi = 0; mi < 4; ++mi)
#pragma unroll
            for (int ni = 0; ni < 4; ++ni)
                acc[mi][ni] = __builtin_amdgcn_mfma_f32_16x16x32_bf16(af[mi], bfr[ni], acc[mi][ni], 0, 0, 0);
    }

#pragma unroll
    for (int ni = 0; ni < 4; ++ni) {
        int col = nbase + wc * 64 + ni * 16 + lr;
        float bv = HAS_BIAS ? bias[col] : 0.f;
#pragma unroll
        for (int mi = 0; mi < 4; ++mi) {
#pragma unroll
            for (int j = 0; j < 4; ++j) {
                int row = mbase + wr * 64 + mi * 16 + lg + j;
                float vv = acc[mi][ni][j] * alpha + bv;
                if (SILU) vv = vv / (1.f + __expf(-vv));
                if (RES) vv += resid[(size_t)row * N + col];
                if (STORE == 0) {
                    ((float*)outp)[(size_t)row * N + col] = vv;
                } else if (STORE == 1) {
                    ((short*)outp)[(size_t)row * N + col] = f2bf(vv);
                } else {  // STORE == 3: fused QKV
                    int seg = col >> 10;
                    int c = col & 1023;
                    if (seg == 0) {
                        ((short*)outp)[(size_t)row * H_ + c] = f2bf(vv);
                    } else if (seg == 1) {
                        ((short*)outp2)[(size_t)row * H_ + c] = f2bf(vv);
                    } else {
                        int bb = row / T_, t = row % T_;
                        ((short*)outp3)[((size_t)(bb * HEADS_ + (c >> 6)) * HD_ + (c & 63)) * T_ + t] = f2bf(vv);
                    }
                }
            }
        }
    }
}

// ---------------- 8-phase 256x256 GEMM (T2+T3+T4+T5), f32 output -------------
// C = A(bf16[M,K]) * Bt(bf16[N,K])^T.  Requires M%256==0, N%256==0, K%128==0.
// 512 threads / 8 waves (2Mx4N), LDS 128 KiB double-buffered, XOR-swizzled.
__global__ __launch_bounds__(512, 2) void k_gemm8(const short* __restrict__ A,
                                                  const short* __restrict__ Bt,
                                                  float* __restrict__ C,
                                                  int M, int N, int K) {
    __shared__ short As[2 * 256 * 64];   // 64 KiB
    __shared__ short Bs[2 * 256 * 64];   // 64 KiB
    int tid = threadIdx.x;
    int lane = tid & 63, w = tid >> 6;
    int wr = w >> 2, wc = w & 3;         // 2 x 4 waves; wave owns 128x64 of C
    int lr = lane & 15, hi = lane >> 4;

    // bijective XCD swizzle (m204 form; works for any nwg)
    int mtiles = M >> 8;
    int nwg = gridDim.x;
    int q = nwg >> 3, r = nwg & 7;
    int xcd = blockIdx.x & 7, lid = blockIdx.x >> 3;
    int wgid = (xcd < r ? xcd * (q + 1) : r * (q + 1) + (xcd - r) * q) + lid;
    int rp = wgid % mtiles, cp = wgid / mtiles;   // M-major: B-panel reuse in L2

    const short* Ab = A + (size_t)rp * 256 * K;
    const short* Bb = Bt + (size_t)cp * 256 * K;

    // staging constants: thread t covers LDS linear 16B slots t and t+512 of a
    // 128-row half-tile. Linear dest (global_load_lds constraint) + inverse-
    // swizzled per-lane global source; reads apply the same XOR (rule #21).
    int r0 = tid >> 3;                              // row within half (load 0)
    int gcol = ((tid & 7) ^ (r0 & 7)) * 8;          // bf16 col within 64-k tile

    // fragment read addressing (byte offsets into a 256x64 bf16 tile)
    int koff0 = (hi * 16) ^ ((lr & 7) << 4);
    int koff1 = (64 + hi * 16) ^ ((lr & 7) << 4);
    int arow[8], brow[4];
#pragma unroll
    for (int m = 0; m < 8; ++m) arow[m] = (wr * 128 + m * 16 + lr) * 128;
#pragma unroll
    for (int n = 0; n < 4; ++n) brow[n] = (wc * 64 + n * 16 + lr) * 128;

    f32x4 acc[8][4] = {};
    short8 aF[4][2], bF[4][2];
    const char* Ac = (const char*)As;
    const char* Bc = (const char*)Bs;

    auto stage = [&](const short* Gb, char* Lb, int tau, int hf) {
        const short* g0 = Gb + (size_t)(hf * 128 + r0) * K + tau * 64 + gcol;
        char* l = Lb + (tau & 1) * 32768 + hf * 16384;
        gload_lds16(g0, l + tid * 16);
        gload_lds16(g0 + (size_t)64 * K, l + (tid + 512) * 16);
    };
    auto lda4 = [&](const char* base, int roff) {
#pragma unroll
        for (int m = 0; m < 4; ++m) {
            aF[m][0] = *(const short8*)(base + arow[roff + m] + koff0);
            aF[m][1] = *(const short8*)(base + arow[roff + m] + koff1);
        }
    };
    auto ldb2 = [&](const char* base, int noff) {
#pragma unroll
        for (int n = 0; n < 2; ++n) {
            bF[noff + n][0] = *(const short8*)(base + brow[noff + n] + koff0);
            bF[noff + n][1] = *(const short8*)(base + brow[noff + n] + koff1);
        }
    };

#define MFMA_QUAD(MOFF, NOFF)                                                          \
    __builtin_amdgcn_s_setprio(1);                                                     \
    _Pragma("unroll") for (int m = 0; m < 4; ++m) {                                    \
        _Pragma("unroll") for (int n = 0; n < 2; ++n) {                                \
            acc[MOFF + m][NOFF + n] = __builtin_amdgcn_mfma_f32_16x16x32_bf16(         \
                aF[m][0], bF[NOFF + n][0], acc[MOFF + m][NOFF + n], 0, 0, 0);          \
            acc[MOFF + m][NOFF + n] = __builtin_amdgcn_mfma_f32_16x16x32_bf16(         \
                aF[m][1], bF[NOFF + n][1], acc[MOFF + m][NOFF + n], 0, 0, 0);          \
        }                                                                              \
    }                                                                                  \
    __builtin_amdgcn_s_setprio(0);

    int NK = K >> 6;
    // prologue: fully stage tiles 0 (buf0) and 1 (buf1)
    stage(Ab, (char*)As, 0, 0); stage(Ab, (char*)As, 0, 1);
    stage(Bb, (char*)Bs, 0, 0); stage(Bb, (char*)Bs, 0, 1);
    stage(Ab, (char*)As, 1, 0); stage(Ab, (char*)As, 1, 1);
    stage(Bb, (char*)Bs, 1, 0); stage(Bb, (char*)Bs, 1, 1);
    asm volatile("s_waitcnt vmcnt(0)" ::: "memory");
    BAR();

    int niters = NK >> 1;
    for (int it = 0; it < niters; ++it) {
        bool st = it < niters - 1;
        int u2 = 2 * it + 2, v2 = 2 * it + 3;   // tiles staged this iter
        const char* a0 = Ac;            const char* b0 = Bc;            // buf0
        const char* a1 = Ac + 32768;    const char* b1 = Bc + 32768;    // buf1

        // ===== tile u = 2*it (buf0), phases 1-4 =====
        // ph1: rows0-3 x cols0-1
        lda4(a0, 0); ldb2(b0, 0);
        BAR();
        MFMA_QUAD(0, 0);
        BAR();
        // ph2: rows0-3 x cols2-3 (B of tile u fully read after this phase)
        ldb2(b0, 2);
        BAR();
        MFMA_QUAD(0, 2);
        BAR();
        // ph3: rows4-7 x cols0-1 (A of tile u fully read after this phase)
        lda4(a0, 4);
        if (st) stage(Bb, (char*)Bs, u2, 0);
        BAR();
        MFMA_QUAD(4, 0);
        BAR();
        // ph4: rows4-7 x cols2-3
        if (st) stage(Bb, (char*)Bs, u2, 1);
        BAR();
        MFMA_QUAD(4, 2);
        asm volatile("s_waitcnt vmcnt(4)" ::: "memory");   // tile v fully landed
        BAR();

        // ===== tile v = 2*it+1 (buf1), phases 5-8 =====
        // ph5
        lda4(a1, 0); ldb2(b1, 0);
        if (st) stage(Ab, (char*)As, u2, 0);
        BAR();
        MFMA_QUAD(0, 0);
        BAR();
        // ph6
        ldb2(b1, 2);
        if (st) stage(Ab, (char*)As, u2, 1);
        BAR();
        MFMA_QUAD(0, 2);
        BAR();
        // ph7
        lda4(a1, 4);
        if (st) stage(Bb, (char*)Bs, v2, 0);
        BAR();
        MFMA_QUAD(4, 0);
        BAR();
        // ph8
        if (st) { stage(Bb, (char*)Bs, v2, 1); stage(Ab, (char*)As, v2, 0); stage(Ab, (char*)As, v2, 1); }
        BAR();
        MFMA_QUAD(4, 2);
        asm volatile("s_waitcnt vmcnt(8)" ::: "memory");   // tile u2 fully landed
        BAR();
    }

    // epilogue: C[row=(lane>>4)*4+j, col=lane&15] per fragment
    int crow = rp * 256 + wr * 128 + hi * 4;
    int ccol = cp * 256 + wc * 64 + lr;
#pragma unroll
    for (int m = 0; m < 8; ++m)
#pragma unroll
        for (int n = 0; n < 4; ++n) {
#pragma unroll
            for (int j = 0; j < 4; ++j)
                C[(size_t)(crow + m * 16 + j) * N + ccol + n * 16] = acc[m][n][j];
        }
#undef MFMA_QUAD
}

// ---------------- flash attention ----------------
__global__ __launch_bounds__(256) void k_attn(const short* __restrict__ q,
                                              const short* __restrict__ k,
                                              const short* __restrict__ vT,
                                              short* __restrict__ out) {
    int qt = blockIdx.x, head = blockIdx.y, b = blockIdx.z;
    int qbase = qt * 64;
    __shared__ short Qs[64][72];
    __shared__ short Ps[4][16][72];
    int tid = threadIdx.x, lane = tid & 63, w = tid >> 6;
    int lr = lane & 15, lg4 = (lane >> 4) * 4, lk8 = (lane >> 4) * 8;

#pragma unroll
    for (int c = 0; c < 2; ++c) {
        int chunk = tid + 256 * c;
        int row = chunk >> 3, h8 = (chunk & 7) * 8;
        *(short8*)&Qs[row][h8] =
            *(const short8*)&q[(size_t)(b * T_ + qbase + row) * H_ + head * HD_ + h8];
    }
    __syncthreads();

    short8 qf[2];
    qf[0] = *(short8*)&Qs[w * 16 + lr][lk8];
    qf[1] = *(short8*)&Qs[w * 16 + lr][32 + lk8];

    f32x4 o[4] = {};
    float m[4] = {-1e30f, -1e30f, -1e30f, -1e30f};
    float lsum[4] = {0.f, 0.f, 0.f, 0.f};

    for (int kt = 0; kt <= qt; ++kt) {
        int kb = kt * 64;
        f32x4 s[4] = {};
#pragma unroll
        for (int ks = 0; ks < 2; ++ks) {
#pragma unroll
            for (int f = 0; f < 4; ++f) {
                short8 kf = *(const short8*)&k[(size_t)(b * T_ + kb + f * 16 + lr) * H_ +
                                               head * HD_ + ks * 32 + lk8];
                s[f] = __builtin_amdgcn_mfma_f32_16x16x32_bf16(qf[ks], kf, s[f], 0, 0, 0);
            }
        }
        if (kt == qt) {
#pragma unroll
            for (int f = 0; f < 4; ++f) {
                int key = kb + f * 16 + lr;
#pragma unroll
                for (int j = 0; j < 4; ++j) {
                    int qrow = qbase + w * 16 + lg4 + j;
                    if (key > qrow) s[f][j] = -1e30f;
                }
            }
        }
#pragma unroll
        for (int j = 0; j < 4; ++j) {
            float mx = fmaxf(fmaxf(s[0][j], s[1][j]), fmaxf(s[2][j], s[3][j]));
#pragma unroll
            for (int off = 1; off < 16; off <<= 1) mx = fmaxf(mx, __shfl_xor(mx, off, 64));
            float mnew = fmaxf(m[j], mx);
            float sc = __expf(m[j] - mnew);
            m[j] = mnew;
            float rs = 0.f;
#pragma unroll
            for (int f = 0; f < 4; ++f) {
                float p = __expf(s[f][j] - mnew);
                s[f][j] = p;
                rs += p;
            }
#pragma unroll
            for (int off = 1; off < 16; off <<= 1) rs += __shfl_xor(rs, off, 64);
            lsum[j] = lsum[j] * sc + rs;
#pragma unroll
            for (int f = 0; f < 4; ++f) o[f][j] *= sc;
#pragma unroll
            for (int f = 0; f < 4; ++f) Ps[w][lg4 + j][f * 16 + lr] = f2bf(s[f][j]);
        }
#pragma unroll
        for (int ks2 = 0; ks2 < 2; ++ks2) {
            short8 pf = *(short8*)&Ps[w][lr][ks2 * 32 + lk8];
#pragma unroll
            for (int f = 0; f < 4; ++f) {
                short8 vf = *(const short8*)&vT[((size_t)(b * HEADS_ + head) * HD_ + f * 16 + lr) * T_ +
                                                kb + ks2 * 32 + lk8];
                o[f] = __builtin_amdgcn_mfma_f32_16x16x32_bf16(pf, vf, o[f], 0, 0, 0);
            }
        }
    }
#pragma unroll
    for (int f = 0; f < 4; ++f)
#pragma unroll
        for (int j = 0; j < 4; ++j) {
            float val = o[f][j] / lsum[j];
            out[(size_t)(b * T_ + qbase + w * 16 + lg4 + j) * H_ + head * HD_ + f * 16 + lr] =
                f2bf(val);
        }
}

// ---------------- launch ----------------
extern "C" void kernel_launch(void* const* d_in, const int* in_sizes, int n_in,
                              void* d_out, int out_size, void* d_ws, size_t ws_size,
                              hipStream_t stream) {
    const float* prefix = (const float*)d_in[0];
    const int* ids = (const int*)d_in[1];
    const float* emb = (const float*)d_in[2];
    const float* Wq = (const float*)d_in[3];
    const float* Wk = (const float*)d_in[4];
    const float* Wv = (const float*)d_in[5];
    const float* Wo = (const float*)d_in[6];
    const float* g1 = (const float*)d_in[7];
    const float* b1 = (const float*)d_in[8];
    const float* g2 = (const float*)d_in[9];
    const float* b2 = (const float*)d_in[10];
    const float* W1 = (const float*)d_in[11];
    const float* bm1 = (const float*)d_in[12];
    const float* W2 = (const float*)d_in[13];
    const float* bm2 = (const float*)d_in[14];
    const float* gf = (const float*)d_in[15];
    const float* bf = (const float*)d_in[16];
    const float* Whead = (const float*)d_in[17];
    float* out = (float*)d_out;

    char* wsp = (char*)d_ws;
    float* x = (float*)wsp;   wsp += (size_t)BT_ * H_ * 4;
    short* h = (short*)wsp;   wsp += (size_t)BT_ * H_ * 2;
    short* qb = (short*)wsp;  wsp += (size_t)BT_ * H_ * 2;
    short* kb = (short*)wsp;  wsp += (size_t)BT_ * H_ * 2;
    short* vT = (short*)wsp;  wsp += (size_t)BT_ * H_ * 2;
    short* ao = (short*)wsp;  wsp += (size_t)BT_ * H_ * 2;
    short* mid = (short*)wsp; wsp += (size_t)BT_ * F_ * 2;
    // bf16-transposed weights [N][K]
    short* WqkvT = (short*)wsp; wsp += (size_t)NL_ * 3 * H_ * H_ * 2;
    short* WoT = (short*)wsp;   wsp += (size_t)NL_ * H_ * H_ * 2;
    short* W1T = (short*)wsp;   wsp += (size_t)NL_ * H_ * F_ * 2;
    short* W2T = (short*)wsp;   wsp += (size_t)NL_ * F_ * H_ * 2;
    short* WhT = (short*)wsp;   wsp += (size_t)H_ * V_ * 2;

    dim3 blk(256);
    for (int l = 0; l < NL_; ++l) {
        size_t o1 = (size_t)l * H_ * H_;
        size_t oq = (size_t)l * 3 * H_ * H_;
        k_cvt_t<<<dim3(H_ / 32, H_ / 32), blk, 0, stream>>>(Wq + o1, WqkvT + oq, H_, H_, 0.125f);
        k_cvt_t<<<dim3(H_ / 32, H_ / 32), blk, 0, stream>>>(Wk + o1, WqkvT + oq + (size_t)H_ * H_, H_, H_, 1.f);
        k_cvt_t<<<dim3(H_ / 32, H_ / 32), blk, 0, stream>>>(Wv + o1, WqkvT + oq + (size_t)2 * H_ * H_, H_, H_, 1.f);
        k_cvt_t<<<dim3(H_ / 32, H_ / 32), blk, 0, stream>>>(Wo + o1, WoT + o1, H_, H_, 1.f);
        size_t o2 = (size_t)l * H_ * F_;
        k_cvt_t<<<dim3(F_ / 32, H_ / 32), blk, 0, stream>>>(W1 + o2, W1T + o2, H_, F_, 1.f);
        k_cvt_t<<<dim3(H_ / 32, F_ / 32), blk, 0, stream>>>(W2 + o2, W2T + o2, F_, H_, 1.f);
    }
    k_cvt_t<<<dim3(V_ / 32, H_ / 32), blk, 0, stream>>>(Whead, WhT, H_, V_, 1.f);

    k_embed<<<BT_, blk, 0, stream>>>(prefix, ids, emb, x);
    for (int l = 0; l < NL_; ++l) {
        size_t o1 = (size_t)l * H_ * H_;
        size_t oq = (size_t)l * 3 * H_ * H_;
        size_t o2 = (size_t)l * H_ * F_;
        k_ln<<<BT_, blk, 0, stream>>>(x, g1 + l * H_, b1 + l * H_, h);
        // fused QKV: N = 3072, grid 24*24 = 576
        k_gemm<3, false, false, false><<<dim3(576), blk, 0, stream>>>(
            h, WqkvT + oq, nullptr, nullptr, qb, kb, vT, BT_, 3 * H_, H_, 1.f);
        k_attn<<<dim3(T_ / 64, HEADS_, B_), blk, 0, stream>>>(qb, kb, vT, ao);
        k_gemm<0, false, false, true><<<dim3(192), blk, 0, stream>>>(
            ao, WoT + o1, nullptr, x, x, nullptr, nullptr, BT_, H_, H_, 1.f);
        k_ln<<<BT_, blk, 0, stream>>>(x, g2 + l * H_, b2 + l * H_, h);
        k_gemm<1, true, true, false><<<dim3(768), blk, 0, stream>>>(
            h, W1T + o2, bm1 + (size_t)l * F_, nullptr, mid, nullptr, nullptr, BT_, F_, H_, 1.f);
        k_gemm<0, true, false, true><<<dim3(192), blk, 0, stream>>>(
            mid, W2T + o2, bm2 + (size_t)l * H_, x, x, nullptr, nullptr, BT_, H_, F_, 1.f);
    }
    k_ln<<<BT_, blk, 0, stream>>>(x, gf, bf, h);
    // head GEMM: 8-phase 256x256 kernel, grid 12*125 = 1500
    k_gemm8<<<dim3((BT_ / 256) * (V_ / 256)), dim3(512), 0, stream>>>(
        h, WhT, out, BT_, V_, H_);
}